// Round 9
// baseline (313.310 us; speedup 1.0000x reference)
//
#include <hip/hip_runtime.h>

// out = LIF16(x @ W^T + b), x:[32768,512] f32, W:[512,512] f32, b:[512] f32.
//
// CORRECTNESS INVARIANT (rounds 0-8; do not break):
// Reference cur = SINGLE sequential ascending-k fp32 FMA chain (one
// accumulator per C element, k=0..511 ascending), then ONE bias add; LIF in
// fp32 RN, source identical to round-3/4/6/7/8 passing kernels (absmax 0.0).
// K-splits / reassociation forbidden.
//
// Round-9 theory: R6-R8 all plateau at ~243 us / ~68% VALUBusy with 8
// waves/CU. Unified VGPR+AGPR budget (~216/thread) caps occupancy at 2
// waves/SIMD -> 193K idle cyc/CU of unhidden ds_read/barrier latency.
// Change: 512-thread blocks with 8x8 micro-tile (64 acc, ~110 total regs
// <= 128) -> 16 waves/CU (4/SIMD). Same BM=256/BN=128 tiles, same grid
// (512 blocks = 2/CU), same dbuf single-barrier K-loop, same LIF epilogue.
// Accepts 0.75->1.0 B/FMA LDS traffic in exchange for 2x latency hiding.

typedef float v4f __attribute__((ext_vector_type(4)));

#define BM 256
#define BN 128
#define BK 16
#define LDA (BM + 4)   // 260 floats: rows 16B-aligned, 2-way-max bank aliasing
#define LDB (BN + 4)   // 132

__global__ __launch_bounds__(512, 4)
void lif_gemm_f32(const float* __restrict__ x,    // [B, K]
                  const float* __restrict__ W,    // [H, K]
                  const float* __restrict__ bias, // [H]
                  float* __restrict__ out,        // [B, H]
                  int K, int H)
{
    __shared__ __align__(16) float As[2][BK][LDA];   // k-major: As[p][k][m]
    __shared__ __align__(16) float Bs[2][BK][LDB];   // k-major: Bs[p][k][n]

    const int tid = threadIdx.x;
    const int tn  = tid & 15;        // 16 N-µtiles: cols tn*4 and 64+tn*4
    const int tmi = tid >> 4;        // 32 M-µtiles: rows tmi*4 and 128+tmi*4
    const int n0  = blockIdx.x * BN; // N fastest: consecutive blocks share A
    const int m0  = blockIdx.y * BM;

    // Staging: A tile 256x16 -> 8 floats/thread; B tile 128x16 -> 4/thread.
    const int ra = tid >> 1;         // 0..255
    const int kc = (tid & 1) << 3;   // 0 or 8
    const int rb = tid >> 2;         // 0..127
    const int kb = (tid & 3) << 2;   // 0,4,8,12

    const float* xg = x + (size_t)(m0 + ra) * K + kc;
    const float* wg = W + (size_t)(n0 + rb) * K + kb;

    float acc[8][8];
#pragma unroll
    for (int i = 0; i < 8; ++i)
#pragma unroll
        for (int j = 0; j < 8; ++j)
            acc[i][j] = 0.0f;

    // prefetch tile 0 into registers
    v4f a0 = *(const v4f*)(xg);
    v4f a1 = *(const v4f*)(xg + 4);
    v4f b0 = *(const v4f*)(wg);

    int pp = 0;
    for (int k0 = 0; k0 < K; k0 += BK) {
        float (*Asp)[LDA] = As[pp];
        float (*Bsp)[LDB] = Bs[pp];

        // stage tile k0 (held in regs) -> LDS buf pp
#pragma unroll
        for (int i = 0; i < 4; ++i) {
            Asp[kc + i][ra]     = a0[i];
            Asp[kc + 4 + i][ra] = a1[i];
            Bsp[kb + i][rb]     = b0[i];
        }
        __syncthreads();             // single barrier per iteration (R7 proof)

        // prefetch tile k0+BK (whole compute section to land)
        const int kn = (k0 + BK < K) ? (k0 + BK) : k0;  // tail: harmless reload
        a0 = *(const v4f*)(xg + kn);
        a1 = *(const v4f*)(xg + kn + 4);
        b0 = *(const v4f*)(wg + kn);

#pragma unroll
        for (int k = 0; k < BK; ++k) {   // ascending k: order is load-bearing
            const v4f af0 = *(const v4f*)&Asp[k][tmi * 4];
            const v4f af1 = *(const v4f*)&Asp[k][128 + tmi * 4];
            const v4f blo = *(const v4f*)&Bsp[k][tn * 4];
            const v4f bhi = *(const v4f*)&Bsp[k][64 + tn * 4];

#pragma unroll
            for (int i = 0; i < 8; ++i) {
                const float a = (i < 4) ? af0[i] : af1[i - 4];
#pragma unroll
                for (int j = 0; j < 8; ++j) {
                    const float b = (j < 4) ? blo[j] : bhi[j - 4];
                    acc[i][j] = fmaf(a, b, acc[i][j]);
                }
            }
        }
        pp ^= 1;
    }

    // Epilogue: + bias (single fp32 add), 16-step fp32 LIF (identical source
    // to the round-3/4/6/7/8 passing kernels), store count/16.
    float bcol[8];
#pragma unroll
    for (int j = 0; j < 8; ++j) {
        const int col = (j < 4) ? (tn * 4 + j) : (64 + tn * 4 + (j - 4));
        bcol[j] = bias[n0 + col];
    }

#pragma unroll
    for (int i = 0; i < 8; ++i) {
        const int row = m0 + ((i < 4) ? (tmi * 4 + i) : (128 + tmi * 4 + (i - 4)));
        float res[8];
#pragma unroll
        for (int j = 0; j < 8; ++j) {
            const float cur = acc[i][j] + bcol[j];
            float v = 0.0f;
            int cnt = 0;
#pragma unroll
            for (int t = 0; t < 16; ++t) {
                v = v + (cur - v) * 0.5f;    // == v + (cur - v)/2, RN-identical
                const bool s = (v >= 1.0f);  // == (v - 1.0f) >= 0 in fp32
                cnt += s ? 1 : 0;
                v = s ? 0.0f : v;
            }
            res[j] = (float)cnt * 0.0625f;   // exact multiple of 1/16
        }
        float* op = out + (size_t)row * H + n0;
        *(v4f*)(op + tn * 4)      = (v4f){res[0], res[1], res[2], res[3]};
        *(v4f*)(op + 64 + tn * 4) = (v4f){res[4], res[5], res[6], res[7]};
    }
}

extern "C" void kernel_launch(void* const* d_in, const int* in_sizes, int n_in,
                              void* d_out, int out_size, void* d_ws, size_t ws_size,
                              hipStream_t stream) {
    const float* x    = (const float*)d_in[0];
    const float* W    = (const float*)d_in[1];
    const float* bias = (const float*)d_in[2];
    float* out = (float*)d_out;

    const int K = 512;
    const int H = 512;
    const int B = in_sizes[0] / K;   // 32768

    dim3 grid(H / BN, B / BM);       // (4, 128) = 512 blocks = 2/CU exactly
    dim3 block(512);
    lif_gemm_f32<<<grid, block, 0, stream>>>(x, W, bias, out, K, H);
}